// Round 1
// baseline (24.155 us; speedup 1.0000x reference)
//
#include <hip/hip_runtime.h>

// SparseIF: multi-step integrate-and-fire, soft reset (v_reset=None), th=1.0
//   v += c[t]; spike = (v >= 1) ? 1 : 0; v -= spike;  out[t] = spike
// Shapes: current [T=64, B=32, D=8192] f32, out same. Pure streaming:
// 64 MB in + 64 MB out => HBM roofline ~20.3 us @ 6.3 TB/s.

#define T_STEPS 64
#define N_NEUR  (32 * 8192)      // B*D = 262144
#define VEC     4
#define NV      (N_NEUR / VEC)   // 65536 float4 columns

__global__ __launch_bounds__(256)
void sparse_if_kernel(const float4* __restrict__ in, float4* __restrict__ out) {
    const int tid = blockIdx.x * blockDim.x + threadIdx.x;  // 0..NV-1
    // Column tid of the [T][NV] float4 matrix; stride NV between timesteps.
    float4 v = make_float4(0.f, 0.f, 0.f, 0.f);

#pragma unroll
    for (int t = 0; t < T_STEPS; ++t) {
        const int idx = tid + t * NV;           // < 64*65536 = 2^22, fits int
        float4 c = in[idx];

        v.x += c.x; v.y += c.y; v.z += c.z; v.w += c.w;

        const float sx = (v.x >= 1.0f) ? 1.0f : 0.0f;
        const float sy = (v.y >= 1.0f) ? 1.0f : 0.0f;
        const float sz = (v.z >= 1.0f) ? 1.0f : 0.0f;
        const float sw = (v.w >= 1.0f) ? 1.0f : 0.0f;

        v.x -= sx; v.y -= sy; v.z -= sz; v.w -= sw;   // soft reset (th=1)

        out[idx] = make_float4(sx, sy, sz, sw);
    }
}

extern "C" void kernel_launch(void* const* d_in, const int* in_sizes, int n_in,
                              void* d_out, int out_size, void* d_ws, size_t ws_size,
                              hipStream_t stream) {
    const float4* in  = reinterpret_cast<const float4*>(d_in[0]);
    float4*       out = reinterpret_cast<float4*>(d_out);

    const int threads = 256;
    const int blocks  = NV / threads;  // 256 blocks -> 1 per CU
    sparse_if_kernel<<<blocks, threads, 0, stream>>>(in, out);
}